// Round 6
// baseline (409.935 us; speedup 1.0000x reference)
//
#include <hip/hip_runtime.h>
#include <math.h>

#define NPTS 65536
#define NBLK_SN 256   // stats/norm blocks (<= 1 per CU -> co-resident)

using half8   = __attribute__((ext_vector_type(8))) _Float16;
using half4   = __attribute__((ext_vector_type(4))) _Float16;
using floatx4 = __attribute__((ext_vector_type(4))) float;

// ---------------------------------------------------------------------------
// k_prep: weights -> f16 [64 d][1024 kc'] with kc' = c*16 + k (k=15 row zero);
//         features -> f16 table featH[N][64]; zero the spin counter.
// ---------------------------------------------------------------------------
__global__ __launch_bounds__(256) void k_prep(
    const float* __restrict__ ow, const float* __restrict__ w,
    const float* __restrict__ feat,
    _Float16* __restrict__ owt, _Float16* __restrict__ wt,
    _Float16* __restrict__ featH, unsigned int* __restrict__ ctr)
{
  if (blockIdx.x == 0 && threadIdx.x == 0) *ctr = 0u;
  int b = blockIdx.x;
  if (b < 256) {                       // 256*256 == 65536 == 64*1024
    int i = b * 256 + threadIdx.x;
    int d = i >> 10, kc = i & 1023, c = kc >> 4, k = kc & 15;
    owt[i] = (k < 15 && d < 60) ? (_Float16)ow[(k * 64 + c) * 60 + d] : (_Float16)0.f;
    wt[i]  = (k < 15) ? (_Float16)w[(k * 64 + c) * 64 + d] : (_Float16)0.f;
  } else {                             // 4096*256 == 1048576 == N*64/4
    int j = (b - 256) * 256 + threadIdx.x;
    float4 f = ((const float4*)feat)[j];
    half4 h = {(_Float16)f.x, (_Float16)f.y, (_Float16)f.z, (_Float16)f.w};
    ((half4*)featH)[j] = h;
  }
}

// ---------------------------------------------------------------------------
// Fused deformable KPConv. 16 pts/block, 4 waves x 4 pts, 3 blocks/CU.
// Transpose: each lane owns 4 neighbor rows x 1 channel-chunk -> 8 b64 LDS
// writes at uniform 4/bank (floor). fT chunk swizzle pc = chunk ^ S(c),
// S(c)=((c>>3)^c)&3; row swizzle rr = c ^ ((c>>3)&1). Rows 32/33 go
// untransposed to fxh and fold in via VALU rank-2 (bpermute redistribution).
// GEMMs in 2 half-K phases (wfh halved; ct2/3 held in regs).
// ---------------------------------------------------------------------------
__global__ __launch_bounds__(256, 3) void k_fused(
    const float* __restrict__ query, const float* __restrict__ support,
    const int* __restrict__ nidx, const _Float16* __restrict__ featH,
    const float* __restrict__ kpts, const float* __restrict__ obias,
    const _Float16* __restrict__ owt, const _Float16* __restrict__ wt,
    float* __restrict__ outx)
{
  __shared__ float                  np[3][16][34];   // x/y/z planes, f32
  __shared__ unsigned short         sidx[16][34];
  __shared__ __align__(16) _Float16 fT[4][2048];     // per-wave, nbr 0..31
  __shared__ __align__(16) _Float16 fxh[2][4][64];   // rows 32/33 [row][wave][c]
  __shared__ __align__(16) _Float16 wfh[16 * 520];   // [pt][c'*16+k], half-K
  __shared__ float                  dk[16][64];      // def_kp(45)+mod(15), f32

  const int tid  = threadIdx.x;
  const int wave = tid >> 6, lane = tid & 63;
  const int quad = lane >> 4, mm = lane & 15;
  const int rq = lane >> 3, ch = lane & 7;
  const int base = blockIdx.x * 16;
  _Float16* fTw = fT[wave];
  unsigned int* fTw32 = (unsigned int*)fTw;
  const floatx4 fz = {0.f, 0.f, 0.f, 0.f};
  const int me = (mm < 15) ? mm : 14;   // row 15 of conv A is discarded

  // ---- stage neighbor displacements (f32 planes) + indices ----
  for (int s = tid; s < 544; s += 256) {
    int pt = s / 34, a = s - pt * 34;
    int n = base + pt;
    int id = nidx[n * 34 + a];
    np[0][pt][a] = support[id * 3 + 0] - query[n * 3 + 0];
    np[1][pt][a] = support[id * 3 + 1] - query[n * 3 + 1];
    np[2][pt][a] = support[id * 3 + 2] - query[n * 3 + 2];
    sidx[pt][a] = (unsigned short)id;
  }
  __syncthreads();

  // ---- gather: lane owns rows 4rq..4rq+3, chunk ch; lanes<16 own row 32/33 ----
  auto load_g = [&](int pl, uint4* G, uint4& GX) {
    #pragma unroll
    for (int i = 0; i < 4; ++i) {
      int id = (int)sidx[pl][rq * 4 + i];
      G[i] = *(const uint4*)(featH + (id << 6) + (ch << 3));
    }
    if (lane < 16) {
      int id = (int)sidx[pl][32 + (lane >> 3)];
      GX = *(const uint4*)(featH + (id << 6) + ((lane & 7) << 3));
    }
  };
  auto transpose_g = [&](const uint4* G, const uint4& GX) {
    const uint* g0 = (const uint*)&G[0];
    const uint* g1 = (const uint*)&G[1];
    const uint* g2 = (const uint*)&G[2];
    const uint* g3 = (const uint*)&G[3];
    #pragma unroll
    for (int cc = 0; cc < 8; ++cc) {
      int c = ch * 8 + cc;
      uint sel = (cc & 1) ? 0x07060302u : 0x05040100u;
      int di = cc >> 1;
      uint2 U;
      U.x = __builtin_amdgcn_perm(g1[di], g0[di], sel);   // rows 4rq+0,+1
      U.y = __builtin_amdgcn_perm(g3[di], g2[di], sel);   // rows 4rq+2,+3
      int rr = c ^ (ch & 1);
      int pc = (rq >> 1) ^ ((ch ^ cc) & 3);
      *(uint2*)(fTw32 + rr * 16 + pc * 4 + (rq & 1) * 2) = U;
    }
    if (lane < 16)
      *(uint4*)(&fxh[lane >> 3][wave][(lane & 7) * 8]) = GX;
  };

  // ---- f32 influence for one neighbor pair (pj = pair index) ----
  auto infl2 = [&](int pl, int pj, float kx, float ky, float kz,
                   float& w0, float& w1) {
    float2 px = *(const float2*)&np[0][pl][2 * pj];
    float2 py = *(const float2*)&np[1][pl][2 * pj];
    float2 pz = *(const float2*)&np[2][pl][2 * pj];
    float dx = px.x - kx, dy = py.x - ky, dz = pz.x - kz;
    w0 = fmaxf(1.f - 2.f * sqrtf(dx * dx + dy * dy + dz * dz), 0.f);
    dx = px.y - kx; dy = py.y - ky; dz = pz.y - kz;
    w1 = fmaxf(1.f - 2.f * sqrtf(dx * dx + dy * dy + dz * dz), 0.f);
  };

  // ---- one conv point: 4 MFMA (nbr 0..31) + rank-2 (nbr 32,33), x mod.
  //      writes ct0/1 to wfh, returns ct2/3 in hold[2] ----
  auto conv_point = [&](int pl, float kx, float ky, float kz, const float* md,
                        floatx4* hold) {
    half8 a0;
    #pragma unroll
    for (int u = 0; u < 4; ++u) {
      float w0, w1;
      infl2(pl, quad * 4 + u, kx, ky, kz, w0, w1);
      a0[2 * u] = (_Float16)w0; a0[2 * u + 1] = (_Float16)w1;
    }
    float w32, w33;
    infl2(pl, 16, kx, ky, kz, w32, w33);   // rows 32,33 at kp = me
    float w32r[4], w33r[4];
    #pragma unroll
    for (int r = 0; r < 4; ++r) {
      int src = (quad * 4 + r) << 2;
      w32r[r] = __int_as_float(__builtin_amdgcn_ds_bpermute(src, __float_as_int(w32)));
      w33r[r] = __int_as_float(__builtin_amdgcn_ds_bpermute(src, __float_as_int(w33)));
    }

    floatx4 acc[4];
    #pragma unroll
    for (int ct = 0; ct < 4; ++ct) {
      int c  = ct * 16 + mm;
      int rr = c ^ ((c >> 3) & 1);
      int pc = quad ^ (((c >> 3) ^ c) & 3);
      half8 b = *(const half8*)(fTw + rr * 32 + pc * 8);
      acc[ct] = __builtin_amdgcn_mfma_f32_16x16x32_f16(a0, b, fz, 0, 0, 0);
    }
    #pragma unroll
    for (int ct = 0; ct < 4; ++ct) {
      int c = ct * 16 + mm;
      float flo = (float)fxh[0][wave][c], fhi = (float)fxh[1][wave][c];
      #pragma unroll
      for (int r = 0; r < 4; ++r)
        acc[ct][r] = (acc[ct][r] + w32r[r] * flo + w33r[r] * fhi) * md[r];
    }

    _Float16* wp = wfh + pl * 520;
    #pragma unroll
    for (int ct = 0; ct < 2; ++ct) {
      half4 h = {(_Float16)acc[ct][0], (_Float16)acc[ct][1],
                 (_Float16)acc[ct][2], (_Float16)acc[ct][3]};
      *(half4*)(wp + (ct * 16 + mm) * 16 + quad * 4) = h;
    }
    hold[0] = acc[2]; hold[1] = acc[3];
  };

  auto write_hold = [&](const floatx4 (*hold)[2]) {
    #pragma unroll
    for (int pp = 0; pp < 4; ++pp) {
      _Float16* wp = wfh + (wave * 4 + pp) * 520;
      #pragma unroll
      for (int ct = 0; ct < 2; ++ct) {
        const floatx4& a = hold[pp][ct];
        half4 h = {(_Float16)a[0], (_Float16)a[1], (_Float16)a[2], (_Float16)a[3]};
        *(half4*)(wp + (ct * 16 + mm) * 16 + quad * 4) = h;
      }
    }
  };

  auto gemm_half = [&](const _Float16* bmat, int koff, floatx4& A, floatx4& B) {
    const _Float16* brow = bmat + (wave * 16 + mm) * 1024 + koff;
    const _Float16* arow = wfh + mm * 520;
    #pragma unroll
    for (int k2 = 0; k2 < 16; ++k2) {
      half8 af = *(const half8*)(arow + k2 * 32 + quad * 8);
      half8 bf = *(const half8*)(brow + k2 * 32 + quad * 8);
      if (k2 & 1) B = __builtin_amdgcn_mfma_f32_16x16x32_f16(af, bf, B, 0, 0, 0);
      else        A = __builtin_amdgcn_mfma_f32_16x16x32_f16(af, bf, A, 0, 0, 0);
    }
  };

  uint4 G[2][4], GX[2];
  floatx4 hold[4][2];
  const float one4[4] = {1.f, 1.f, 1.f, 1.f};

  // ================= conv0 (rigid kernel points) =================
  {
    float k0x = kpts[me * 3 + 0], k0y = kpts[me * 3 + 1], k0z = kpts[me * 3 + 2];
    load_g(wave * 4, G[0], GX[0]);
    #pragma unroll
    for (int pp = 0; pp < 4; ++pp) {
      int pl = wave * 4 + pp;
      if (pp < 3) load_g(pl + 1, G[(pp + 1) & 1], GX[(pp + 1) & 1]);
      transpose_g(G[pp & 1], GX[pp & 1]);
      conv_point(pl, k0x, k0y, k0z, one4, hold[pp]);
    }
  }
  load_g(wave * 4, G[0], GX[0]);   // prefetch conv1 p0 under GEMM0
  __syncthreads();

  // ================= GEMM0 (2 phases) -> def_kp + modulations =================
  {
    floatx4 A = fz, B = fz;
    gemm_half(owt, 0, A, B);
    __syncthreads();
    write_hold(hold);
    __syncthreads();
    gemm_half(owt, 512, A, B);
    int d = wave * 16 + mm;
    float bv = (d < 60) ? obias[d] : 0.f;
    float kv = (d < 45) ? kpts[d] : 0.f;
    #pragma unroll
    for (int r = 0; r < 4; ++r) {
      int pt = quad * 4 + r;
      float v = A[r] + B[r] + bv;
      float o = (d < 45) ? (kv + 0.5f * v)            // def_kp = kp + f0*EXTENT
                         : (2.f / (1.f + expf(-v)));  // modulation
      dk[pt][d] = o;
    }
  }
  __syncthreads();   // dk ready; GEMM0 wfh reads done

  // ================= conv1 (deformed kernel points) =================
  #pragma unroll
  for (int pp = 0; pp < 4; ++pp) {
    int pl = wave * 4 + pp;
    if (pp < 3) load_g(pl + 1, G[(pp + 1) & 1], GX[(pp + 1) & 1]);
    float kx = dk[pl][me * 3 + 0], ky = dk[pl][me * 3 + 1], kz = dk[pl][me * 3 + 2];
    float md[4];
    #pragma unroll
    for (int r = 0; r < 4; ++r) {
      int k = quad * 4 + r;
      md[r] = (k < 15) ? dk[pl][45 + k] : 1.f;
    }
    transpose_g(G[pp & 1], GX[pp & 1]);
    conv_point(pl, kx, ky, kz, md, hold[pp]);
  }
  __syncthreads();

  // ================= GEMM1 (2 phases) -> x (pre-BN) =================
  {
    floatx4 A = fz, B = fz;
    gemm_half(wt, 0, A, B);
    __syncthreads();
    write_hold(hold);
    __syncthreads();
    gemm_half(wt, 512, A, B);
    int d = wave * 16 + mm;
    #pragma unroll
    for (int r = 0; r < 4; ++r)
      outx[(base + quad * 4 + r) * 64 + d] = A[r] + B[r];
  }
}

// ---------------------------------------------------------------------------
// Fused BN stats + reduce + norm + LeakyReLU: one kernel, NBLK_SN blocks
// (co-resident), device-scope atomic spin barrier between stats and norm.
// ---------------------------------------------------------------------------
__global__ __launch_bounds__(256) void k_statsnorm(
    float* __restrict__ x, float* __restrict__ part,
    unsigned int* __restrict__ ctr,
    const float* __restrict__ gamma, const float* __restrict__ beta)
{
  __shared__ float red[512];
  __shared__ float sS[64], sB[64];
  const int tid = threadIdx.x, b = blockIdx.x;
  const int c = tid & 63, g = tid >> 6;

  // phase 1: block-local per-channel sums over 256 rows
  float s1 = 0.f, s2 = 0.f;
  const int r0 = b * 256;
  #pragma unroll 4
  for (int it = 0; it < 64; ++it) {
    float v = x[(r0 + it * 4 + g) * 64 + c];
    s1 += v; s2 += v * v;
  }
  red[tid] = s1; red[256 + tid] = s2;
  __syncthreads();
  if (tid < 128) {
    int cc = tid & 63, which = tid >> 6;
    int o = which * 256;
    float s = red[o + cc] + red[o + cc + 64] + red[o + cc + 128] + red[o + cc + 192];
    part[b * 128 + which * 64 + cc] = s;
  }
  __threadfence();
  __syncthreads();
  if (tid == 0) {
    __hip_atomic_fetch_add(ctr, 1u, __ATOMIC_RELEASE, __HIP_MEMORY_SCOPE_AGENT);
    while (__hip_atomic_load(ctr, __ATOMIC_ACQUIRE, __HIP_MEMORY_SCOPE_AGENT)
           < (unsigned)NBLK_SN) { __builtin_amdgcn_s_sleep(2); }
  }
  __syncthreads();

  // phase 2: every block reduces all partials -> per-channel scale/shift
  {
    int c2 = tid & 127, h = tid >> 7;
    float s = 0.f;
    for (int bb = h * (NBLK_SN / 2); bb < (h + 1) * (NBLK_SN / 2); ++bb)
      s += part[bb * 128 + c2];
    red[tid] = s;
    __syncthreads();
    if (tid < 64) {
      float sum = red[tid] + red[128 + tid];
      float sq  = red[64 + tid] + red[192 + tid];
      float mean = sum * (1.f / NPTS);
      float var  = sq * (1.f / NPTS) - mean * mean;
      float sc = rsqrtf(var + 1e-6f) * gamma[tid];
      sS[tid] = sc;
      sB[tid] = beta[tid] - mean * sc;
    }
    __syncthreads();
  }

  // phase 3: normalize + LeakyReLU (grid-stride float4)
  float4* x4 = (float4*)x;
  #pragma unroll 4
  for (int it = 0; it < 16; ++it) {
    int i = b * 4096 + it * 256 + tid;
    float4 v = x4[i];
    int c0 = (i & 15) * 4;
    float o[4] = {v.x, v.y, v.z, v.w};
    #pragma unroll
    for (int j = 0; j < 4; ++j) {
      float y = o[j] * sS[c0 + j] + sB[c0 + j];
      o[j] = (y >= 0.f) ? y : 0.1f * y;
    }
    float4 rv = {o[0], o[1], o[2], o[3]};
    x4[i] = rv;
  }
}

// ---------------------------------------------------------------------------
extern "C" void kernel_launch(void* const* d_in, const int* in_sizes, int n_in,
                              void* d_out, int out_size, void* d_ws, size_t ws_size,
                              hipStream_t stream)
{
  const float* query   = (const float*)d_in[0];
  const float* support = (const float*)d_in[1];
  const int*   nidx    = (const int*)d_in[2];
  const float* feat    = (const float*)d_in[3];
  const float* weight  = (const float*)d_in[4];
  const float* oweight = (const float*)d_in[5];
  const float* obias   = (const float*)d_in[6];
  const float* gamma   = (const float*)d_in[7];
  const float* beta    = (const float*)d_in[8];
  const float* kpts    = (const float*)d_in[9];
  float* x = (float*)d_out;

  char* ws = (char*)d_ws;
  _Float16*     featH = (_Float16*)ws;                  // 8,388,608 B
  _Float16*     owt   = (_Float16*)(ws + 8388608);      //   131,072 B
  _Float16*     wt    = (_Float16*)(ws + 8519680);      //   131,072 B
  float*        part  = (float*)(ws + 8650752);         //   131,072 B
  unsigned int* ctr   = (unsigned int*)(ws + 8781824);  //         4 B

  k_prep<<<4352, 256, 0, stream>>>(oweight, weight, feat, owt, wt, featH, ctr);
  k_fused<<<4096, 256, 0, stream>>>(query, support, nidx, featH, kpts, obias,
                                    owt, wt, x);
  k_statsnorm<<<NBLK_SN, 256, 0, stream>>>(x, part, ctr, gamma, beta);
}

// Round 7
// 403.938 us; speedup vs baseline: 1.0148x; 1.0148x over previous
//
#include <hip/hip_runtime.h>
#include <math.h>

#define NPTS 65536
#define NBLK_SN 256   // stats/norm blocks (<= 1 per CU -> co-resident)

using half8   = __attribute__((ext_vector_type(8))) _Float16;
using half4   = __attribute__((ext_vector_type(4))) _Float16;
using floatx4 = __attribute__((ext_vector_type(4))) float;

// ---------------------------------------------------------------------------
// k_prep: weights -> f16 [64 d][1024 kc'] with kc' = c*16 + k (k=15 row zero);
//         features -> f16 table featH[N][64]; zero the spin counter.
// ---------------------------------------------------------------------------
__global__ __launch_bounds__(256) void k_prep(
    const float* __restrict__ ow, const float* __restrict__ w,
    const float* __restrict__ feat,
    _Float16* __restrict__ owt, _Float16* __restrict__ wt,
    _Float16* __restrict__ featH, unsigned int* __restrict__ ctr)
{
  if (blockIdx.x == 0 && threadIdx.x == 0) *ctr = 0u;
  int b = blockIdx.x;
  if (b < 256) {                       // 256*256 == 65536 == 64*1024
    int i = b * 256 + threadIdx.x;
    int d = i >> 10, kc = i & 1023, c = kc >> 4, k = kc & 15;
    owt[i] = (k < 15 && d < 60) ? (_Float16)ow[(k * 64 + c) * 60 + d] : (_Float16)0.f;
    wt[i]  = (k < 15) ? (_Float16)w[(k * 64 + c) * 64 + d] : (_Float16)0.f;
  } else {                             // 4096*256 == 1048576 == N*64/4
    int j = (b - 256) * 256 + threadIdx.x;
    float4 f = ((const float4*)feat)[j];
    half4 h = {(_Float16)f.x, (_Float16)f.y, (_Float16)f.z, (_Float16)f.w};
    ((half4*)featH)[j] = h;
  }
}

// ---------------------------------------------------------------------------
// Packed shared memory: fixed C++ layout, 45760 B total -> 3 blocks/CU.
// (Round-6 lesson: separate __shared__ decls let the compiler pad to 54272 B
// and silently drop to 2 blocks/CU.)
// ---------------------------------------------------------------------------
struct __align__(16) Smem {
  float          np[3][16][34];            //  6528  x/y/z displacement planes
  unsigned short sidx[16][34];             //  1088
  _Float16       fT[4][2048];              // 16384  per-wave transposed feats
  _Float16       fxh[2][4][64];            //  1024  rows 32/33 [row][wave][c]
  _Float16       wfh[16 * 520];            // 16640  [pt][c'*16+k], half-K
  float          dk[16][64];               //  4096  def_kp(45)+mod(15)
};                                         // total 45760

// ---------------------------------------------------------------------------
// Fused deformable KPConv. 16 pts/block, 4 waves x 4 pts, 3 blocks/CU.
// Transpose: each lane owns 4 neighbor rows x 1 channel-chunk -> 8 b64 LDS
// writes at uniform 4/bank. fT chunk swizzle pc = chunk ^ (((c>>3)^c)&3);
// row swizzle rr = c ^ ((c>>3)&1). Rows 32/33 untransposed in fxh, folded in
// via VALU rank-2 (bpermute). GEMMs in 2 half-K phases (ct2/3 held in regs).
// ---------------------------------------------------------------------------
__global__ __launch_bounds__(256, 3) void k_fused(
    const float* __restrict__ query, const float* __restrict__ support,
    const int* __restrict__ nidx, const _Float16* __restrict__ featH,
    const float* __restrict__ kpts, const float* __restrict__ obias,
    const _Float16* __restrict__ owt, const _Float16* __restrict__ wt,
    float* __restrict__ outx)
{
  __shared__ Smem sm;

  const int tid  = threadIdx.x;
  const int wave = tid >> 6, lane = tid & 63;
  const int quad = lane >> 4, mm = lane & 15;
  const int rq = lane >> 3, ch = lane & 7;
  const int base = blockIdx.x * 16;
  _Float16* fTw = sm.fT[wave];
  unsigned int* fTw32 = (unsigned int*)fTw;
  const floatx4 fz = {0.f, 0.f, 0.f, 0.f};
  const int me = (mm < 15) ? mm : 14;   // row 15 of conv A is discarded

  // ---- stage neighbor displacements (f32 planes) + indices ----
  for (int s = tid; s < 544; s += 256) {
    int pt = s / 34, a = s - pt * 34;
    int n = base + pt;
    int id = nidx[n * 34 + a];
    sm.np[0][pt][a] = support[id * 3 + 0] - query[n * 3 + 0];
    sm.np[1][pt][a] = support[id * 3 + 1] - query[n * 3 + 1];
    sm.np[2][pt][a] = support[id * 3 + 2] - query[n * 3 + 2];
    sm.sidx[pt][a] = (unsigned short)id;
  }
  __syncthreads();

  // ---- gather: lane owns rows 4rq..4rq+3, chunk ch; lanes<16 own rows 32/33 ----
  auto load_g = [&](int pl, uint4* G, uint4& GX) {
    #pragma unroll
    for (int i = 0; i < 4; ++i) {
      int id = (int)sm.sidx[pl][rq * 4 + i];
      G[i] = *(const uint4*)(featH + (id << 6) + (ch << 3));
    }
    if (lane < 16) {
      int id = (int)sm.sidx[pl][32 + (lane >> 3)];
      GX = *(const uint4*)(featH + (id << 6) + ((lane & 7) << 3));
    }
  };
  auto transpose_g = [&](const uint4* G, const uint4& GX) {
    const uint* g0 = (const uint*)&G[0];
    const uint* g1 = (const uint*)&G[1];
    const uint* g2 = (const uint*)&G[2];
    const uint* g3 = (const uint*)&G[3];
    #pragma unroll
    for (int cc = 0; cc < 8; ++cc) {
      int c = ch * 8 + cc;
      uint sel = (cc & 1) ? 0x07060302u : 0x05040100u;
      int di = cc >> 1;
      uint2 U;
      U.x = __builtin_amdgcn_perm(g1[di], g0[di], sel);   // rows 4rq+0,+1
      U.y = __builtin_amdgcn_perm(g3[di], g2[di], sel);   // rows 4rq+2,+3
      int rr = c ^ (ch & 1);
      int pc = (rq >> 1) ^ ((ch ^ cc) & 3);
      *(uint2*)(fTw32 + rr * 16 + pc * 4 + (rq & 1) * 2) = U;
    }
    if (lane < 16)
      *(uint4*)(&sm.fxh[lane >> 3][wave][(lane & 7) * 8]) = GX;
  };

  // ---- f32 influence for one neighbor pair (pj = pair index) ----
  auto infl2 = [&](int pl, int pj, float kx, float ky, float kz,
                   float& w0, float& w1) {
    float2 px = *(const float2*)&sm.np[0][pl][2 * pj];
    float2 py = *(const float2*)&sm.np[1][pl][2 * pj];
    float2 pz = *(const float2*)&sm.np[2][pl][2 * pj];
    float dx = px.x - kx, dy = py.x - ky, dz = pz.x - kz;
    w0 = fmaxf(1.f - 2.f * sqrtf(dx * dx + dy * dy + dz * dz), 0.f);
    dx = px.y - kx; dy = py.y - ky; dz = pz.y - kz;
    w1 = fmaxf(1.f - 2.f * sqrtf(dx * dx + dy * dy + dz * dz), 0.f);
  };

  // ---- one conv point: 4 MFMA (nbr 0..31) + rank-2 (nbr 32,33), x mod.
  //      writes ct0/1 to wfh, returns ct2/3 in hold[2] ----
  auto conv_point = [&](int pl, float kx, float ky, float kz, const float* md,
                        floatx4* hold) {
    half8 a0;
    #pragma unroll
    for (int u = 0; u < 4; ++u) {
      float w0, w1;
      infl2(pl, quad * 4 + u, kx, ky, kz, w0, w1);
      a0[2 * u] = (_Float16)w0; a0[2 * u + 1] = (_Float16)w1;
    }
    float w32, w33;
    infl2(pl, 16, kx, ky, kz, w32, w33);   // rows 32,33 at kp = me
    float w32r[4], w33r[4];
    #pragma unroll
    for (int r = 0; r < 4; ++r) {
      int src = (quad * 4 + r) << 2;
      w32r[r] = __int_as_float(__builtin_amdgcn_ds_bpermute(src, __float_as_int(w32)));
      w33r[r] = __int_as_float(__builtin_amdgcn_ds_bpermute(src, __float_as_int(w33)));
    }

    floatx4 acc[4];
    #pragma unroll
    for (int ct = 0; ct < 4; ++ct) {
      int c  = ct * 16 + mm;
      int rr = c ^ ((c >> 3) & 1);
      int pc = quad ^ (((c >> 3) ^ c) & 3);
      half8 b = *(const half8*)(fTw + rr * 32 + pc * 8);
      acc[ct] = __builtin_amdgcn_mfma_f32_16x16x32_f16(a0, b, fz, 0, 0, 0);
    }
    #pragma unroll
    for (int ct = 0; ct < 4; ++ct) {
      int c = ct * 16 + mm;
      float flo = (float)sm.fxh[0][wave][c], fhi = (float)sm.fxh[1][wave][c];
      #pragma unroll
      for (int r = 0; r < 4; ++r)
        acc[ct][r] = (acc[ct][r] + w32r[r] * flo + w33r[r] * fhi) * md[r];
    }

    _Float16* wp = sm.wfh + pl * 520;
    #pragma unroll
    for (int ct = 0; ct < 2; ++ct) {
      half4 h = {(_Float16)acc[ct][0], (_Float16)acc[ct][1],
                 (_Float16)acc[ct][2], (_Float16)acc[ct][3]};
      *(half4*)(wp + (ct * 16 + mm) * 16 + quad * 4) = h;
    }
    hold[0] = acc[2]; hold[1] = acc[3];
  };

  auto write_hold = [&](const floatx4 (*hold)[2]) {
    #pragma unroll
    for (int pp = 0; pp < 4; ++pp) {
      _Float16* wp = sm.wfh + (wave * 4 + pp) * 520;
      #pragma unroll
      for (int ct = 0; ct < 2; ++ct) {
        const floatx4& a = hold[pp][ct];
        half4 h = {(_Float16)a[0], (_Float16)a[1], (_Float16)a[2], (_Float16)a[3]};
        *(half4*)(wp + (ct * 16 + mm) * 16 + quad * 4) = h;
      }
    }
  };

  auto gemm_half = [&](const _Float16* bmat, int koff, floatx4& A, floatx4& B) {
    const _Float16* brow = bmat + (wave * 16 + mm) * 1024 + koff;
    const _Float16* arow = sm.wfh + mm * 520;
    #pragma unroll
    for (int k2 = 0; k2 < 16; ++k2) {
      half8 af = *(const half8*)(arow + k2 * 32 + quad * 8);
      half8 bf = *(const half8*)(brow + k2 * 32 + quad * 8);
      if (k2 & 1) B = __builtin_amdgcn_mfma_f32_16x16x32_f16(af, bf, B, 0, 0, 0);
      else        A = __builtin_amdgcn_mfma_f32_16x16x32_f16(af, bf, A, 0, 0, 0);
    }
  };

  uint4 G[2][4], GX[2];
  floatx4 hold[4][2];
  const float one4[4] = {1.f, 1.f, 1.f, 1.f};

  // ================= conv0 (rigid kernel points) =================
  {
    float k0x = kpts[me * 3 + 0], k0y = kpts[me * 3 + 1], k0z = kpts[me * 3 + 2];
    load_g(wave * 4, G[0], GX[0]);
    #pragma unroll
    for (int pp = 0; pp < 4; ++pp) {
      int pl = wave * 4 + pp;
      if (pp < 3) load_g(pl + 1, G[(pp + 1) & 1], GX[(pp + 1) & 1]);
      transpose_g(G[pp & 1], GX[pp & 1]);
      conv_point(pl, k0x, k0y, k0z, one4, hold[pp]);
    }
  }
  load_g(wave * 4, G[0], GX[0]);   // prefetch conv1 p0 under GEMM0
  __syncthreads();

  // ================= GEMM0 (2 phases) -> def_kp + modulations =================
  {
    floatx4 A = fz, B = fz;
    gemm_half(owt, 0, A, B);
    __syncthreads();
    write_hold(hold);
    __syncthreads();
    gemm_half(owt, 512, A, B);
    int d = wave * 16 + mm;
    float bv = (d < 60) ? obias[d] : 0.f;
    float kv = (d < 45) ? kpts[d] : 0.f;
    #pragma unroll
    for (int r = 0; r < 4; ++r) {
      int pt = quad * 4 + r;
      float v = A[r] + B[r] + bv;
      float o = (d < 45) ? (kv + 0.5f * v)            // def_kp = kp + f0*EXTENT
                         : (2.f / (1.f + expf(-v)));  // modulation
      sm.dk[pt][d] = o;
    }
  }
  __syncthreads();   // dk ready; GEMM0 wfh reads done

  // ================= conv1 (deformed kernel points) =================
  #pragma unroll
  for (int pp = 0; pp < 4; ++pp) {
    int pl = wave * 4 + pp;
    if (pp < 3) load_g(pl + 1, G[(pp + 1) & 1], GX[(pp + 1) & 1]);
    float kx = sm.dk[pl][me * 3 + 0];
    float ky = sm.dk[pl][me * 3 + 1];
    float kz = sm.dk[pl][me * 3 + 2];
    float md[4];
    #pragma unroll
    for (int r = 0; r < 4; ++r) {
      int k = quad * 4 + r;
      md[r] = (k < 15) ? sm.dk[pl][45 + k] : 1.f;
    }
    transpose_g(G[pp & 1], GX[pp & 1]);
    conv_point(pl, kx, ky, kz, md, hold[pp]);
  }
  __syncthreads();

  // ================= GEMM1 (2 phases) -> x (pre-BN) =================
  {
    floatx4 A = fz, B = fz;
    gemm_half(wt, 0, A, B);
    __syncthreads();
    write_hold(hold);
    __syncthreads();
    gemm_half(wt, 512, A, B);
    int d = wave * 16 + mm;
    #pragma unroll
    for (int r = 0; r < 4; ++r)
      outx[(base + quad * 4 + r) * 64 + d] = A[r] + B[r];
  }
}

// ---------------------------------------------------------------------------
// Fused BN stats + reduce + norm + LeakyReLU: one kernel, NBLK_SN blocks
// (co-resident), device-scope atomic spin barrier between stats and norm.
// ---------------------------------------------------------------------------
__global__ __launch_bounds__(256) void k_statsnorm(
    float* __restrict__ x, float* __restrict__ part,
    unsigned int* __restrict__ ctr,
    const float* __restrict__ gamma, const float* __restrict__ beta)
{
  __shared__ float red[512];
  __shared__ float sS[64], sB[64];
  const int tid = threadIdx.x, b = blockIdx.x;
  const int c = tid & 63, g = tid >> 6;

  // phase 1: block-local per-channel sums over 256 rows
  float s1 = 0.f, s2 = 0.f;
  const int r0 = b * 256;
  #pragma unroll 4
  for (int it = 0; it < 64; ++it) {
    float v = x[(r0 + it * 4 + g) * 64 + c];
    s1 += v; s2 += v * v;
  }
  red[tid] = s1; red[256 + tid] = s2;
  __syncthreads();
  if (tid < 128) {
    int cc = tid & 63, which = tid >> 6;
    int o = which * 256;
    float s = red[o + cc] + red[o + cc + 64] + red[o + cc + 128] + red[o + cc + 192];
    part[b * 128 + which * 64 + cc] = s;
  }
  __threadfence();
  __syncthreads();
  if (tid == 0) {
    __hip_atomic_fetch_add(ctr, 1u, __ATOMIC_RELEASE, __HIP_MEMORY_SCOPE_AGENT);
    while (__hip_atomic_load(ctr, __ATOMIC_ACQUIRE, __HIP_MEMORY_SCOPE_AGENT)
           < (unsigned)NBLK_SN) { __builtin_amdgcn_s_sleep(2); }
  }
  __syncthreads();

  // phase 2: every block reduces all partials -> per-channel scale/shift
  {
    int c2 = tid & 127, h = tid >> 7;
    float s = 0.f;
    for (int bb = h * (NBLK_SN / 2); bb < (h + 1) * (NBLK_SN / 2); ++bb)
      s += part[bb * 128 + c2];
    red[tid] = s;
    __syncthreads();
    if (tid < 64) {
      float sum = red[tid] + red[128 + tid];
      float sq  = red[64 + tid] + red[192 + tid];
      float mean = sum * (1.f / NPTS);
      float var  = sq * (1.f / NPTS) - mean * mean;
      float sc = rsqrtf(var + 1e-6f) * gamma[tid];
      sS[tid] = sc;
      sB[tid] = beta[tid] - mean * sc;
    }
    __syncthreads();
  }

  // phase 3: normalize + LeakyReLU (grid-stride float4)
  float4* x4 = (float4*)x;
  #pragma unroll 4
  for (int it = 0; it < 16; ++it) {
    int i = b * 4096 + it * 256 + tid;
    float4 v = x4[i];
    int c0 = (i & 15) * 4;
    float o[4] = {v.x, v.y, v.z, v.w};
    #pragma unroll
    for (int j = 0; j < 4; ++j) {
      float y = o[j] * sS[c0 + j] + sB[c0 + j];
      o[j] = (y >= 0.f) ? y : 0.1f * y;
    }
    float4 rv = {o[0], o[1], o[2], o[3]};
    x4[i] = rv;
  }
}

// ---------------------------------------------------------------------------
extern "C" void kernel_launch(void* const* d_in, const int* in_sizes, int n_in,
                              void* d_out, int out_size, void* d_ws, size_t ws_size,
                              hipStream_t stream)
{
  const float* query   = (const float*)d_in[0];
  const float* support = (const float*)d_in[1];
  const int*   nidx    = (const int*)d_in[2];
  const float* feat    = (const float*)d_in[3];
  const float* weight  = (const float*)d_in[4];
  const float* oweight = (const float*)d_in[5];
  const float* obias   = (const float*)d_in[6];
  const float* gamma   = (const float*)d_in[7];
  const float* beta    = (const float*)d_in[8];
  const float* kpts    = (const float*)d_in[9];
  float* x = (float*)d_out;

  char* ws = (char*)d_ws;
  _Float16*     featH = (_Float16*)ws;                  // 8,388,608 B
  _Float16*     owt   = (_Float16*)(ws + 8388608);      //   131,072 B
  _Float16*     wt    = (_Float16*)(ws + 8519680);      //   131,072 B
  float*        part  = (float*)(ws + 8650752);         //   131,072 B
  unsigned int* ctr   = (unsigned int*)(ws + 8781824);  //         4 B

  k_prep<<<4352, 256, 0, stream>>>(oweight, weight, feat, owt, wt, featH, ctr);
  k_fused<<<4096, 256, 0, stream>>>(query, support, nidx, featH, kpts, obias,
                                    owt, wt, x);
  k_statsnorm<<<NBLK_SN, 256, 0, stream>>>(x, part, ctr, gamma, beta);
}

// Round 8
// 334.725 us; speedup vs baseline: 1.2247x; 1.2068x over previous
//
#include <hip/hip_runtime.h>
#include <math.h>

#define NPTS 65536

using half8   = __attribute__((ext_vector_type(8))) _Float16;
using half4   = __attribute__((ext_vector_type(4))) _Float16;
using floatx4 = __attribute__((ext_vector_type(4))) float;

// ---------------------------------------------------------------------------
// k_prep: weights -> f16 [64 d][1024 kc'] with kc' = c*16 + k (k=15 row zero);
//         features -> f16 table featH[N][64]
// ---------------------------------------------------------------------------
__global__ __launch_bounds__(256) void k_prep(
    const float* __restrict__ ow, const float* __restrict__ w,
    const float* __restrict__ feat,
    _Float16* __restrict__ owt, _Float16* __restrict__ wt,
    _Float16* __restrict__ featH)
{
  int b = blockIdx.x;
  if (b < 256) {                       // 256*256 == 65536 == 64*1024
    int i = b * 256 + threadIdx.x;
    int d = i >> 10, kc = i & 1023, c = kc >> 4, k = kc & 15;
    owt[i] = (k < 15 && d < 60) ? (_Float16)ow[(k * 64 + c) * 60 + d] : (_Float16)0.f;
    wt[i]  = (k < 15) ? (_Float16)w[(k * 64 + c) * 64 + d] : (_Float16)0.f;
  } else {                             // 4096*256 == 1048576 == N*64/4
    int j = (b - 256) * 256 + threadIdx.x;
    float4 f = ((const float4*)feat)[j];
    half4 h = {(_Float16)f.x, (_Float16)f.y, (_Float16)f.z, (_Float16)f.w};
    ((half4*)featH)[j] = h;
  }
}

// ---------------------------------------------------------------------------
// Packed shared memory, 36480 B -> 4 blocks/CU headroom even with the ~320 B
// allocator rounding. (r6/r7 lesson: a lane-guarded register buffer was
// demoted to LDS (+8192 B) and silently cost a whole block/CU.)
// ---------------------------------------------------------------------------
struct __align__(16) Smem {
  _Float16 fT[4][2048];              // 16384  per-wave transposed feats (nbr 0..31)
  _Float16 wfh[16 * 264];            //  8448  [pt][c_local*16+k], quarter-K
  _Float16 fxh[2][4][64];            //  1024  rows 32/33 [row][wave][c]
  float    np[3][16][34];            //  6528  x/y/z displacement planes
  float    dk[16][64];               //  4096  def_kp(45)+mod(15)
};                                   // total 36480

// ---------------------------------------------------------------------------
// Fused deformable KPConv. 16 pts/block, 4 waves x 4 pts, 4 blocks/CU.
// Gather: lane owns rows 4rq..4rq+3 x chunk ch (uint4), unconditional GX for
// rows 32/33. Transpose -> fT via b64 writes (row swizzle rr = c^((c>>3)&1),
// chunk swizzle pc = chunk^(((c>>3)^c)&3)). Conv: 4 MFMA + VALU rank-2 for
// rows 32/33 (bpermute). GEMM: 4 quarter-K phases; ct1..3 held as half4 regs.
// ---------------------------------------------------------------------------
__global__ __launch_bounds__(256, 3) void k_fused(
    const float* __restrict__ query, const float* __restrict__ support,
    const int* __restrict__ nidx, const _Float16* __restrict__ featH,
    const float* __restrict__ kpts, const float* __restrict__ obias,
    const _Float16* __restrict__ owt, const _Float16* __restrict__ wt,
    float* __restrict__ outx)
{
  __shared__ Smem sm;

  const int tid  = threadIdx.x;
  const int wave = tid >> 6, lane = tid & 63;
  const int quad = lane >> 4, mm = lane & 15;
  const int rq = lane >> 3, ch = lane & 7;
  const int base = blockIdx.x * 16;
  _Float16* fTw = sm.fT[wave];
  unsigned int* fTw32 = (unsigned int*)fTw;
  const floatx4 fz = {0.f, 0.f, 0.f, 0.f};
  const int me = (mm < 15) ? mm : 14;   // row 15 of conv A is discarded

  // ---- stage neighbor displacements (f32 planes) ----
  for (int s = tid; s < 544; s += 256) {
    int pt = s / 34, a = s - pt * 34;
    int n = base + pt;
    int id = nidx[n * 34 + a];
    sm.np[0][pt][a] = support[id * 3 + 0] - query[n * 3 + 0];
    sm.np[1][pt][a] = support[id * 3 + 1] - query[n * 3 + 1];
    sm.np[2][pt][a] = support[id * 3 + 2] - query[n * 3 + 2];
  }
  __syncthreads();

  // ---- gather: rows 4rq..4rq+3 chunk ch; GX = rows 32/33 (unconditional) ----
  auto load_g = [&](int pl, uint4* G, uint4& GX) {
    const int nb = (base + pl) * 34;
    #pragma unroll
    for (int i = 0; i < 4; ++i) {
      int id = nidx[nb + rq * 4 + i];
      G[i] = *(const uint4*)(featH + (id << 6) + (ch << 3));
    }
    {
      int l = lane & 15;
      int id = nidx[nb + 32 + (l >> 3)];
      GX = *(const uint4*)(featH + (id << 6) + ((l & 7) << 3));
    }
  };
  auto transpose_g = [&](const uint4* G, const uint4& GX) {
    const uint* g0 = (const uint*)&G[0];
    const uint* g1 = (const uint*)&G[1];
    const uint* g2 = (const uint*)&G[2];
    const uint* g3 = (const uint*)&G[3];
    #pragma unroll
    for (int cc = 0; cc < 8; ++cc) {
      int c = ch * 8 + cc;
      uint sel = (cc & 1) ? 0x07060302u : 0x05040100u;
      int di = cc >> 1;
      uint2 U;
      U.x = __builtin_amdgcn_perm(g1[di], g0[di], sel);   // rows 4rq+0,+1
      U.y = __builtin_amdgcn_perm(g3[di], g2[di], sel);   // rows 4rq+2,+3
      int rr = c ^ (ch & 1);
      int pc = (rq >> 1) ^ ((ch ^ cc) & 3);
      *(uint2*)(fTw32 + rr * 16 + pc * 4 + (rq & 1) * 2) = U;
    }
    if (lane < 16)
      *(uint4*)(&sm.fxh[lane >> 3][wave][(lane & 7) * 8]) = GX;
  };

  // ---- f32 influence for one neighbor pair ----
  auto infl2 = [&](int pl, int pj, float kx, float ky, float kz,
                   float& w0, float& w1) {
    float2 px = *(const float2*)&sm.np[0][pl][2 * pj];
    float2 py = *(const float2*)&sm.np[1][pl][2 * pj];
    float2 pz = *(const float2*)&sm.np[2][pl][2 * pj];
    float dx = px.x - kx, dy = py.x - ky, dz = pz.x - kz;
    w0 = fmaxf(1.f - 2.f * sqrtf(dx * dx + dy * dy + dz * dz), 0.f);
    dx = px.y - kx; dy = py.y - ky; dz = pz.y - kz;
    w1 = fmaxf(1.f - 2.f * sqrtf(dx * dx + dy * dy + dz * dz), 0.f);
  };

  // ---- one conv point: 4 MFMA + rank-2 fold, x md; ct0 -> wfh,
  //      ct1..3 -> holdh (pre-converted half4) ----
  auto conv_point = [&](int pl, float kx, float ky, float kz, const float* md,
                        half4* holdh) {
    half8 a0;
    #pragma unroll
    for (int u = 0; u < 4; ++u) {
      float w0, w1;
      infl2(pl, quad * 4 + u, kx, ky, kz, w0, w1);
      a0[2 * u] = (_Float16)w0; a0[2 * u + 1] = (_Float16)w1;
    }
    float w32, w33;
    infl2(pl, 16, kx, ky, kz, w32, w33);   // rows 32,33 at kp = me
    float w32r[4], w33r[4];
    #pragma unroll
    for (int r = 0; r < 4; ++r) {
      int src = (quad * 4 + r) << 2;
      w32r[r] = __int_as_float(__builtin_amdgcn_ds_bpermute(src, __float_as_int(w32)));
      w33r[r] = __int_as_float(__builtin_amdgcn_ds_bpermute(src, __float_as_int(w33)));
    }

    floatx4 acc[4];
    #pragma unroll
    for (int ct = 0; ct < 4; ++ct) {
      int c  = ct * 16 + mm;
      int rr = c ^ ((c >> 3) & 1);
      int pc = quad ^ (((c >> 3) ^ c) & 3);
      half8 b = *(const half8*)(fTw + rr * 32 + pc * 8);
      acc[ct] = __builtin_amdgcn_mfma_f32_16x16x32_f16(a0, b, fz, 0, 0, 0);
    }
    #pragma unroll
    for (int ct = 0; ct < 4; ++ct) {
      int c = ct * 16 + mm;
      float flo = (float)sm.fxh[0][wave][c], fhi = (float)sm.fxh[1][wave][c];
      #pragma unroll
      for (int r = 0; r < 4; ++r)
        acc[ct][r] = (acc[ct][r] + w32r[r] * flo + w33r[r] * fhi) * md[r];
    }

    // ct0 straight to wfh; ct1..3 kept as packed half4 in registers
    _Float16* wp = sm.wfh + pl * 264;
    half4 h0 = {(_Float16)acc[0][0], (_Float16)acc[0][1],
                (_Float16)acc[0][2], (_Float16)acc[0][3]};
    *(half4*)(wp + mm * 16 + quad * 4) = h0;
    #pragma unroll
    for (int ct = 1; ct < 4; ++ct) {
      half4 h = {(_Float16)acc[ct][0], (_Float16)acc[ct][1],
                 (_Float16)acc[ct][2], (_Float16)acc[ct][3]};
      holdh[ct - 1] = h;
    }
  };

  // ---- write held ct (phase j uses hold index j-1) ----
  auto write_hold = [&](const half4 (*holdh)[3], int j) {
    #pragma unroll
    for (int pp = 0; pp < 4; ++pp)
      *(half4*)(sm.wfh + (wave * 4 + pp) * 264 + mm * 16 + quad * 4) = holdh[pp][j];
  };

  // ---- quarter-K GEMM phase: 8 k-steps over 16 channels ----
  auto gemm_q = [&](const _Float16* bmat, int p, floatx4& A, floatx4& B) {
    const _Float16* brow = bmat + (wave * 16 + mm) * 1024 + p * 256;
    const _Float16* arow = sm.wfh + mm * 264;
    #pragma unroll
    for (int k2 = 0; k2 < 8; ++k2) {
      half8 af = *(const half8*)(arow + k2 * 32 + quad * 8);
      half8 bf = *(const half8*)(brow + k2 * 32 + quad * 8);
      if (k2 & 1) B = __builtin_amdgcn_mfma_f32_16x16x32_f16(af, bf, B, 0, 0, 0);
      else        A = __builtin_amdgcn_mfma_f32_16x16x32_f16(af, bf, A, 0, 0, 0);
    }
  };

  uint4 G[2][4], GX[2];
  half4 holdh[4][3];
  const float one4[4] = {1.f, 1.f, 1.f, 1.f};

  // ================= conv0 (rigid kernel points) =================
  {
    float k0x = kpts[me * 3 + 0], k0y = kpts[me * 3 + 1], k0z = kpts[me * 3 + 2];
    load_g(wave * 4, G[0], GX[0]);
    #pragma unroll
    for (int pp = 0; pp < 4; ++pp) {
      int pl = wave * 4 + pp;
      if (pp < 3) load_g(pl + 1, G[(pp + 1) & 1], GX[(pp + 1) & 1]);
      transpose_g(G[pp & 1], GX[pp & 1]);
      conv_point(pl, k0x, k0y, k0z, one4, holdh[pp]);
    }
  }
  __syncthreads();

  // ================= GEMM0 (4 phases) -> def_kp + modulations =================
  {
    floatx4 A = fz, B = fz;
    gemm_q(owt, 0, A, B);
    #pragma unroll
    for (int p = 1; p < 4; ++p) {
      __syncthreads();
      write_hold(holdh, p - 1);
      __syncthreads();
      gemm_q(owt, p, A, B);
    }
    int d = wave * 16 + mm;
    float bv = (d < 60) ? obias[d] : 0.f;
    float kv = (d < 45) ? kpts[d] : 0.f;
    #pragma unroll
    for (int r = 0; r < 4; ++r) {
      int pt = quad * 4 + r;
      float v = A[r] + B[r] + bv;
      float o = (d < 45) ? (kv + 0.5f * v)            // def_kp = kp + f0*EXTENT
                         : (2.f / (1.f + expf(-v)));  // modulation
      sm.dk[pt][d] = o;
    }
  }
  __syncthreads();   // dk ready; all GEMM0 wfh reads done

  // ================= conv1 (deformed kernel points) =================
  load_g(wave * 4, G[0], GX[0]);
  #pragma unroll
  for (int pp = 0; pp < 4; ++pp) {
    int pl = wave * 4 + pp;
    if (pp < 3) load_g(pl + 1, G[(pp + 1) & 1], GX[(pp + 1) & 1]);
    float kx = sm.dk[pl][me * 3 + 0];
    float ky = sm.dk[pl][me * 3 + 1];
    float kz = sm.dk[pl][me * 3 + 2];
    float md[4];
    #pragma unroll
    for (int r = 0; r < 4; ++r) {
      int k = quad * 4 + r;
      md[r] = (k < 15) ? sm.dk[pl][45 + k] : 1.f;
    }
    transpose_g(G[pp & 1], GX[pp & 1]);
    conv_point(pl, kx, ky, kz, md, holdh[pp]);
  }
  __syncthreads();

  // ================= GEMM1 (4 phases) -> x (pre-BN) =================
  {
    floatx4 A = fz, B = fz;
    gemm_q(wt, 0, A, B);
    #pragma unroll
    for (int p = 1; p < 4; ++p) {
      __syncthreads();
      write_hold(holdh, p - 1);
      __syncthreads();
      gemm_q(wt, p, A, B);
    }
    int d = wave * 16 + mm;
    #pragma unroll
    for (int r = 0; r < 4; ++r)
      outx[(base + quad * 4 + r) * 64 + d] = A[r] + B[r];
  }
}

// ---------------------------------------------------------------------------
// Per-channel batch stats: stats[0..63]=sum, stats[64..127]=sumsq
// (atomic variant — measured faster than partials+reduce or spin-barrier)
// ---------------------------------------------------------------------------
__global__ __launch_bounds__(256) void k_stats(
    const float* __restrict__ x, float* __restrict__ stats)
{
  __shared__ float red[512];
  const int tid = threadIdx.x;
  const int c = tid & 63, g = tid >> 6;
  float s1 = 0.f, s2 = 0.f;
  for (int r = blockIdx.x * 4 + g; r < NPTS; r += 1024) {
    float v = x[r * 64 + c];
    s1 += v; s2 += v * v;
  }
  red[tid] = s1; red[256 + tid] = s2;
  __syncthreads();
  if (tid < 64) {
    s1 = red[tid] + red[tid + 64] + red[tid + 128] + red[tid + 192];
    s2 = red[256 + tid] + red[256 + tid + 64] + red[256 + tid + 128] + red[256 + tid + 192];
    atomicAdd(&stats[c], s1);
    atomicAdd(&stats[64 + c], s2);
  }
}

// ---------------------------------------------------------------------------
// BN (batch stats, biased var, eps=1e-6) + LeakyReLU(0.1), in-place
// ---------------------------------------------------------------------------
__global__ __launch_bounds__(256) void k_norm(
    float* __restrict__ x, const float* __restrict__ stats,
    const float* __restrict__ gamma, const float* __restrict__ beta)
{
  const int i = blockIdx.x * 256 + threadIdx.x;
  float4 v = ((float4*)x)[i];
  const int c0 = (i * 4) & 63;
  float o[4] = {v.x, v.y, v.z, v.w};
  #pragma unroll
  for (int j = 0; j < 4; ++j) {
    int c = c0 + j;
    float mean = stats[c] * (1.f / NPTS);
    float var  = stats[64 + c] * (1.f / NPTS) - mean * mean;
    float s = rsqrtf(var + 1e-6f) * gamma[c];
    float y = (o[j] - mean) * s + beta[c];
    o[j] = (y >= 0.f) ? y : 0.1f * y;
  }
  float4 rv = {o[0], o[1], o[2], o[3]};
  ((float4*)x)[i] = rv;
}

// ---------------------------------------------------------------------------
extern "C" void kernel_launch(void* const* d_in, const int* in_sizes, int n_in,
                              void* d_out, int out_size, void* d_ws, size_t ws_size,
                              hipStream_t stream)
{
  const float* query   = (const float*)d_in[0];
  const float* support = (const float*)d_in[1];
  const int*   nidx    = (const int*)d_in[2];
  const float* feat    = (const float*)d_in[3];
  const float* weight  = (const float*)d_in[4];
  const float* oweight = (const float*)d_in[5];
  const float* obias   = (const float*)d_in[6];
  const float* gamma   = (const float*)d_in[7];
  const float* beta    = (const float*)d_in[8];
  const float* kpts    = (const float*)d_in[9];
  float* x = (float*)d_out;

  char* ws = (char*)d_ws;
  _Float16* featH = (_Float16*)ws;                  // 8,388,608 B
  _Float16* owt   = (_Float16*)(ws + 8388608);      //   131,072 B
  _Float16* wt    = (_Float16*)(ws + 8519680);      //   131,072 B
  float*    stats = (float*)(ws + 8650752);         //       512 B

  hipMemsetAsync(stats, 0, 512, stream);
  k_prep<<<4352, 256, 0, stream>>>(oweight, weight, feat, owt, wt, featH);
  k_fused<<<4096, 256, 0, stream>>>(query, support, nidx, featH, kpts, obias,
                                    owt, wt, x);
  k_stats<<<256, 256, 0, stream>>>(x, stats);
  k_norm<<<4096, 256, 0, stream>>>(x, stats, gamma, beta);
}

// Round 9
// 334.328 us; speedup vs baseline: 1.2261x; 1.0012x over previous
//
#include <hip/hip_runtime.h>
#include <math.h>

#define NPTS 65536

using half8   = __attribute__((ext_vector_type(8))) _Float16;
using half4   = __attribute__((ext_vector_type(4))) _Float16;
using floatx4 = __attribute__((ext_vector_type(4))) float;

// ---------------------------------------------------------------------------
// k_prep: weights -> f16 [64 d][1024 kc'] with kc' = c*16 + k (k=15 row zero);
//         features -> f16 table featH[N][64]; zero stats (replaces memset).
// ---------------------------------------------------------------------------
__global__ __launch_bounds__(256) void k_prep(
    const float* __restrict__ ow, const float* __restrict__ w,
    const float* __restrict__ feat,
    _Float16* __restrict__ owt, _Float16* __restrict__ wt,
    _Float16* __restrict__ featH, float* __restrict__ stats)
{
  int b = blockIdx.x;
  if (b == 4351 && threadIdx.x < 128) stats[threadIdx.x] = 0.f;
  if (b < 256) {                       // 256*256 == 65536 == 64*1024
    int i = b * 256 + threadIdx.x;
    int d = i >> 10, kc = i & 1023, c = kc >> 4, k = kc & 15;
    owt[i] = (k < 15 && d < 60) ? (_Float16)ow[(k * 64 + c) * 60 + d] : (_Float16)0.f;
    wt[i]  = (k < 15) ? (_Float16)w[(k * 64 + c) * 64 + d] : (_Float16)0.f;
  } else {                             // 4096*256 == 1048576 == N*64/4
    int j = (b - 256) * 256 + threadIdx.x;
    float4 f = ((const float4*)feat)[j];
    half4 h = {(_Float16)f.x, (_Float16)f.y, (_Float16)f.z, (_Float16)f.w};
    ((half4*)featH)[j] = h;
  }
}

// ---------------------------------------------------------------------------
// Packed shared memory, 36480 B (alloc ~36864) -> up to 4 blocks/CU.
// ---------------------------------------------------------------------------
struct __align__(16) Smem {
  _Float16 fT[4][2048];              // 16384  per-wave transposed feats (nbr 0..31)
  _Float16 wfh[16 * 264];            //  8448  [pt][c_local*16+k], quarter-K
  _Float16 fxh[2][4][64];            //  1024  rows 32/33 [row][wave][c]
  float    np[3][16][34];            //  6528  x/y/z displacement planes
  float    dk[16][64];               //  4096  def_kp(45)+mod(15)
};                                   // total 36480

// ---------------------------------------------------------------------------
// Fused deformable KPConv. 16 pts/block, 4 waves x 4 pts.
// r8 lesson: NO dynamically-indexed local arrays (scratch demotion);
// r6/r7 lesson: NO lane-guarded register buffers (LDS demotion).
// GEMM: 4 quarter-K phases, hold1/2/3 separate half4[4] arrays, all literal
// indices. Rank-2 fold: (w32,w33) packed f16x2 -> 4 bpermutes per point.
// ---------------------------------------------------------------------------
__global__ __launch_bounds__(256, 3) void k_fused(
    const float* __restrict__ query, const float* __restrict__ support,
    const int* __restrict__ nidx, const _Float16* __restrict__ featH,
    const float* __restrict__ kpts, const float* __restrict__ obias,
    const _Float16* __restrict__ owt, const _Float16* __restrict__ wt,
    float* __restrict__ outx)
{
  __shared__ Smem sm;

  const int tid  = threadIdx.x;
  const int wave = tid >> 6, lane = tid & 63;
  const int quad = lane >> 4, mm = lane & 15;
  const int rq = lane >> 3, ch = lane & 7;
  const int base = blockIdx.x * 16;
  _Float16* fTw = sm.fT[wave];
  unsigned int* fTw32 = (unsigned int*)fTw;
  const floatx4 fz = {0.f, 0.f, 0.f, 0.f};
  const int me = (mm < 15) ? mm : 14;   // row 15 of conv A is discarded

  // ---- stage neighbor displacements (f32 planes) ----
  for (int s = tid; s < 544; s += 256) {
    int pt = s / 34, a = s - pt * 34;
    int n = base + pt;
    int id = nidx[n * 34 + a];
    sm.np[0][pt][a] = support[id * 3 + 0] - query[n * 3 + 0];
    sm.np[1][pt][a] = support[id * 3 + 1] - query[n * 3 + 1];
    sm.np[2][pt][a] = support[id * 3 + 2] - query[n * 3 + 2];
  }
  __syncthreads();

  // ---- gather: rows 4rq..4rq+3 chunk ch; GX = rows 32/33 (unconditional) ----
  auto load_g = [&](int pl, uint4 (&G)[4], uint4& GX) {
    const int nb = (base + pl) * 34;
    #pragma unroll
    for (int i = 0; i < 4; ++i) {
      int id = nidx[nb + rq * 4 + i];
      G[i] = *(const uint4*)(featH + (id << 6) + (ch << 3));
    }
    {
      int l = lane & 15;
      int id = nidx[nb + 32 + (l >> 3)];
      GX = *(const uint4*)(featH + (id << 6) + ((l & 7) << 3));
    }
  };
  auto transpose_g = [&](const uint4 (&G)[4], const uint4& GX) {
    const uint* g0 = (const uint*)&G[0];
    const uint* g1 = (const uint*)&G[1];
    const uint* g2 = (const uint*)&G[2];
    const uint* g3 = (const uint*)&G[3];
    #pragma unroll
    for (int cc = 0; cc < 8; ++cc) {
      int c = ch * 8 + cc;
      uint sel = (cc & 1) ? 0x07060302u : 0x05040100u;
      int di = cc >> 1;
      uint2 U;
      U.x = __builtin_amdgcn_perm(g1[di], g0[di], sel);   // rows 4rq+0,+1
      U.y = __builtin_amdgcn_perm(g3[di], g2[di], sel);   // rows 4rq+2,+3
      int rr = c ^ (ch & 1);
      int pc = (rq >> 1) ^ ((ch ^ cc) & 3);
      *(uint2*)(fTw32 + rr * 16 + pc * 4 + (rq & 1) * 2) = U;
    }
    if (lane < 16)
      *(uint4*)(&sm.fxh[lane >> 3][wave][(lane & 7) * 8]) = GX;
  };

  // ---- f32 influence for one neighbor pair ----
  auto infl2 = [&](int pl, int pj, float kx, float ky, float kz,
                   float& w0, float& w1) {
    float2 px = *(const float2*)&sm.np[0][pl][2 * pj];
    float2 py = *(const float2*)&sm.np[1][pl][2 * pj];
    float2 pz = *(const float2*)&sm.np[2][pl][2 * pj];
    float dx = px.x - kx, dy = py.x - ky, dz = pz.x - kz;
    w0 = fmaxf(1.f - 2.f * sqrtf(dx * dx + dy * dy + dz * dz), 0.f);
    dx = px.y - kx; dy = py.y - ky; dz = pz.y - kz;
    w1 = fmaxf(1.f - 2.f * sqrtf(dx * dx + dy * dy + dz * dz), 0.f);
  };

  // ---- one conv point: 4 MFMA + rank-2 fold (packed bpermute), x md;
  //      ct0 -> wfh, ct1..3 -> o1/o2/o3 (pre-converted half4 refs) ----
  auto conv_point = [&](int pl, float kx, float ky, float kz, const float* md,
                        half4& o1, half4& o2, half4& o3) {
    half8 a0;
    #pragma unroll
    for (int u = 0; u < 4; ++u) {
      float w0, w1;
      infl2(pl, quad * 4 + u, kx, ky, kz, w0, w1);
      a0[2 * u] = (_Float16)w0; a0[2 * u + 1] = (_Float16)w1;
    }
    float w32, w33;
    infl2(pl, 16, kx, ky, kz, w32, w33);   // rows 32,33 at kp = me
    uint packed = (uint)__builtin_bit_cast(unsigned short, (_Float16)w32) |
                  ((uint)__builtin_bit_cast(unsigned short, (_Float16)w33) << 16);
    float w32r[4], w33r[4];
    #pragma unroll
    for (int r = 0; r < 4; ++r) {
      uint pr = (uint)__builtin_amdgcn_ds_bpermute(((quad * 4 + r) << 2),
                                                   (int)packed);
      w32r[r] = (float)__builtin_bit_cast(_Float16, (unsigned short)(pr & 0xffffu));
      w33r[r] = (float)__builtin_bit_cast(_Float16, (unsigned short)(pr >> 16));
    }

    floatx4 acc[4];
    #pragma unroll
    for (int ct = 0; ct < 4; ++ct) {
      int c  = ct * 16 + mm;
      int rr = c ^ ((c >> 3) & 1);
      int pc = quad ^ (((c >> 3) ^ c) & 3);
      half8 b = *(const half8*)(fTw + rr * 32 + pc * 8);
      acc[ct] = __builtin_amdgcn_mfma_f32_16x16x32_f16(a0, b, fz, 0, 0, 0);
    }
    #pragma unroll
    for (int ct = 0; ct < 4; ++ct) {
      int c = ct * 16 + mm;
      float flo = (float)sm.fxh[0][wave][c], fhi = (float)sm.fxh[1][wave][c];
      #pragma unroll
      for (int r = 0; r < 4; ++r)
        acc[ct][r] = (acc[ct][r] + w32r[r] * flo + w33r[r] * fhi) * md[r];
    }

    _Float16* wp = sm.wfh + pl * 264;
    half4 h0 = {(_Float16)acc[0][0], (_Float16)acc[0][1],
                (_Float16)acc[0][2], (_Float16)acc[0][3]};
    *(half4*)(wp + mm * 16 + quad * 4) = h0;
    o1 = half4{(_Float16)acc[1][0], (_Float16)acc[1][1],
               (_Float16)acc[1][2], (_Float16)acc[1][3]};
    o2 = half4{(_Float16)acc[2][0], (_Float16)acc[2][1],
               (_Float16)acc[2][2], (_Float16)acc[2][3]};
    o3 = half4{(_Float16)acc[3][0], (_Float16)acc[3][1],
               (_Float16)acc[3][2], (_Float16)acc[3][3]};
  };

  // ---- quarter-K GEMM phase: 8 k-steps over 16 channels ----
  auto gemm_q = [&](const _Float16* bmat, int p, floatx4& A, floatx4& B) {
    const _Float16* brow = bmat + (wave * 16 + mm) * 1024 + p * 256;
    const _Float16* arow = sm.wfh + mm * 264;
    #pragma unroll
    for (int k2 = 0; k2 < 8; ++k2) {
      half8 af = *(const half8*)(arow + k2 * 32 + quad * 8);
      half8 bf = *(const half8*)(brow + k2 * 32 + quad * 8);
      if (k2 & 1) B = __builtin_amdgcn_mfma_f32_16x16x32_f16(af, bf, B, 0, 0, 0);
      else        A = __builtin_amdgcn_mfma_f32_16x16x32_f16(af, bf, A, 0, 0, 0);
    }
  };

  uint4 G[2][4], GX[2];
  half4 hold1[4], hold2[4], hold3[4];
  const float one4[4] = {1.f, 1.f, 1.f, 1.f};

  // writes one held ct-tile (literal indices only)
  auto write_hold = [&](const half4 (&hh)[4]) {
    #pragma unroll
    for (int pp = 0; pp < 4; ++pp)
      *(half4*)(sm.wfh + (wave * 4 + pp) * 264 + mm * 16 + quad * 4) = hh[pp];
  };

  // ================= conv0 (rigid kernel points) =================
  {
    float k0x = kpts[me * 3 + 0], k0y = kpts[me * 3 + 1], k0z = kpts[me * 3 + 2];
    load_g(wave * 4, G[0], GX[0]);
    #pragma unroll
    for (int pp = 0; pp < 4; ++pp) {
      int pl = wave * 4 + pp;
      if (pp < 3) load_g(pl + 1, G[(pp + 1) & 1], GX[(pp + 1) & 1]);
      transpose_g(G[pp & 1], GX[pp & 1]);
      conv_point(pl, k0x, k0y, k0z, one4, hold1[pp], hold2[pp], hold3[pp]);
    }
  }
  load_g(wave * 4, G[0], GX[0]);   // prefetch conv1 p0 under GEMM0
  __syncthreads();

  // ================= GEMM0 (4 phases) -> def_kp + modulations =================
  {
    floatx4 A = fz, B = fz;
    gemm_q(owt, 0, A, B);
    __syncthreads(); write_hold(hold1); __syncthreads();
    gemm_q(owt, 1, A, B);
    __syncthreads(); write_hold(hold2); __syncthreads();
    gemm_q(owt, 2, A, B);
    __syncthreads(); write_hold(hold3); __syncthreads();
    gemm_q(owt, 3, A, B);
    int d = wave * 16 + mm;
    float bv = (d < 60) ? obias[d] : 0.f;
    float kv = (d < 45) ? kpts[d] : 0.f;
    #pragma unroll
    for (int r = 0; r < 4; ++r) {
      int pt = quad * 4 + r;
      float v = A[r] + B[r] + bv;
      float o = (d < 45) ? (kv + 0.5f * v)            // def_kp = kp + f0*EXTENT
                         : (2.f / (1.f + expf(-v)));  // modulation
      sm.dk[pt][d] = o;
    }
  }
  __syncthreads();   // dk ready; all GEMM0 wfh reads done

  // ================= conv1 (deformed kernel points) =================
  #pragma unroll
  for (int pp = 0; pp < 4; ++pp) {
    int pl = wave * 4 + pp;
    if (pp < 3) load_g(pl + 1, G[(pp + 1) & 1], GX[(pp + 1) & 1]);
    float kx = sm.dk[pl][me * 3 + 0];
    float ky = sm.dk[pl][me * 3 + 1];
    float kz = sm.dk[pl][me * 3 + 2];
    float md[4];
    #pragma unroll
    for (int r = 0; r < 4; ++r) {
      int k = quad * 4 + r;
      md[r] = (k < 15) ? sm.dk[pl][45 + k] : 1.f;
    }
    transpose_g(G[pp & 1], GX[pp & 1]);
    conv_point(pl, kx, ky, kz, md, hold1[pp], hold2[pp], hold3[pp]);
  }
  __syncthreads();

  // ================= GEMM1 (4 phases) -> x (pre-BN) =================
  {
    floatx4 A = fz, B = fz;
    gemm_q(wt, 0, A, B);
    __syncthreads(); write_hold(hold1); __syncthreads();
    gemm_q(wt, 1, A, B);
    __syncthreads(); write_hold(hold2); __syncthreads();
    gemm_q(wt, 2, A, B);
    __syncthreads(); write_hold(hold3); __syncthreads();
    gemm_q(wt, 3, A, B);
    int d = wave * 16 + mm;
    #pragma unroll
    for (int r = 0; r < 4; ++r)
      outx[(base + quad * 4 + r) * 64 + d] = A[r] + B[r];
  }
}

// ---------------------------------------------------------------------------
// Per-channel batch stats: stats[0..63]=sum, stats[64..127]=sumsq
// ---------------------------------------------------------------------------
__global__ __launch_bounds__(256) void k_stats(
    const float* __restrict__ x, float* __restrict__ stats)
{
  __shared__ float red[512];
  const int tid = threadIdx.x;
  const int c = tid & 63, g = tid >> 6;
  float s1 = 0.f, s2 = 0.f;
  for (int r = blockIdx.x * 4 + g; r < NPTS; r += 1024) {
    float v = x[r * 64 + c];
    s1 += v; s2 += v * v;
  }
  red[tid] = s1; red[256 + tid] = s2;
  __syncthreads();
  if (tid < 64) {
    s1 = red[tid] + red[tid + 64] + red[tid + 128] + red[tid + 192];
    s2 = red[256 + tid] + red[256 + tid + 64] + red[256 + tid + 128] + red[256 + tid + 192];
    atomicAdd(&stats[c], s1);
    atomicAdd(&stats[64 + c], s2);
  }
}

// ---------------------------------------------------------------------------
// BN (batch stats, biased var, eps=1e-6) + LeakyReLU(0.1), in-place
// ---------------------------------------------------------------------------
__global__ __launch_bounds__(256) void k_norm(
    float* __restrict__ x, const float* __restrict__ stats,
    const float* __restrict__ gamma, const float* __restrict__ beta)
{
  const int i = blockIdx.x * 256 + threadIdx.x;
  float4 v = ((float4*)x)[i];
  const int c0 = (i * 4) & 63;
  float o[4] = {v.x, v.y, v.z, v.w};
  #pragma unroll
  for (int j = 0; j < 4; ++j) {
    int c = c0 + j;
    float mean = stats[c] * (1.f / NPTS);
    float var  = stats[64 + c] * (1.f / NPTS) - mean * mean;
    float s = rsqrtf(var + 1e-6f) * gamma[c];
    float y = (o[j] - mean) * s + beta[c];
    o[j] = (y >= 0.f) ? y : 0.1f * y;
  }
  float4 rv = {o[0], o[1], o[2], o[3]};
  ((float4*)x)[i] = rv;
}

// ---------------------------------------------------------------------------
extern "C" void kernel_launch(void* const* d_in, const int* in_sizes, int n_in,
                              void* d_out, int out_size, void* d_ws, size_t ws_size,
                              hipStream_t stream)
{
  const float* query   = (const float*)d_in[0];
  const float* support = (const float*)d_in[1];
  const int*   nidx    = (const int*)d_in[2];
  const float* feat    = (const float*)d_in[3];
  const float* weight  = (const float*)d_in[4];
  const float* oweight = (const float*)d_in[5];
  const float* obias   = (const float*)d_in[6];
  const float* gamma   = (const float*)d_in[7];
  const float* beta    = (const float*)d_in[8];
  const float* kpts    = (const float*)d_in[9];
  float* x = (float*)d_out;

  char* ws = (char*)d_ws;
  _Float16* featH = (_Float16*)ws;                  // 8,388,608 B
  _Float16* owt   = (_Float16*)(ws + 8388608);      //   131,072 B
  _Float16* wt    = (_Float16*)(ws + 8519680);      //   131,072 B
  float*    stats = (float*)(ws + 8650752);         //       512 B

  k_prep<<<4352, 256, 0, stream>>>(oweight, weight, feat, owt, wt, featH, stats);
  k_fused<<<4096, 256, 0, stream>>>(query, support, nidx, featH, kpts, obias,
                                    owt, wt, x);
  k_stats<<<256, 256, 0, stream>>>(x, stats);
  k_norm<<<4096, 256, 0, stream>>>(x, stats, gamma, beta);
}